// Round 7
// baseline (148.363 us; speedup 1.0000x reference)
//
#include <hip/hip_runtime.h>
#include <hip/hip_fp16.h>

// SIREN via MFMA f16, A=weights / B=activations, 2 point-groups per wave.
// D[16 feat x 16 pt] = W[16 feat x 32 in] * X[32 in x 16 pt].
// Wave owns 128 points (two 64-pt groups) sharing weight frags; groups are
// staggered per layer so g0's LDS round-trip hides under g1's compute.
// Feature permutation sigma(p)=16*((p>>2)&1)+4*(p>>3)+(p&3) makes each lane's
// 8 outputs per m-tile LDS-contiguous -> ONE ds_write_b128 per tile.
// Weight hi/lo f16 split (two chained MFMAs) keeps weights exact; only
// activation f16 quant remains. 30/(2pi) folded into weights/biases at prep.
// LDS: row/point, 32 f16 = 16 dw + 4 pad = 20 dw stride; 40 KB/block.

#define SINSCALE 4.774648292756860f   // 30/(2*pi)
#define RSD 20                         // act row stride in dwords

typedef __attribute__((ext_vector_type(8))) _Float16 half8;
typedef __attribute__((ext_vector_type(2))) __fp16 fp16x2;
typedef __attribute__((ext_vector_type(4))) float f32x4;

union S16 { uint4 u4; half8 h; };
union PK { fp16x2 h2; unsigned int u; };
union HU { __half h; unsigned short u; };

__device__ __forceinline__ float fast_sigmoid(float t) {
    float e = __builtin_amdgcn_exp2f(t * -1.4426950408889634f);
    return 1.0f / (1.0f + e);
}

__device__ __forceinline__ unsigned int pk2(float a, float b) {
    PK p; p.h2 = __builtin_amdgcn_cvt_pkrtz(a, b);
    return p.u;
}

// k-slot p holds activation of physical feature sigma(p)
__device__ __forceinline__ int sigma(int p) {
    return 16 * ((p >> 2) & 1) + 4 * (p >> 3) + (p & 3);
}

// ---- prep: 19 blocks x 64 lanes ----
// A-frag (16x16x32 f16): lane holds A[m=lane&15][k=(lane>>4)*8+j], j=0..7,
// with k permuted by sigma: A[m][p] = W[row(m)][sigma(p)] * SINSCALE.
// frag s<16: l=s>>2 (w1..w4), u=(s>>1)&1 (feature tile: rows 16u+m), h=s&1 (hi/lo).
// s=16+h: w5 (u=0). Block 18: biases bsc, w0s/b0s in sigma output order.
__global__ void prep_kernel(const float* __restrict__ w1, const float* __restrict__ w2,
                            const float* __restrict__ w3, const float* __restrict__ w4,
                            const float* __restrict__ w5,
                            const float* __restrict__ b1, const float* __restrict__ b2,
                            const float* __restrict__ b3, const float* __restrict__ b4,
                            const float* __restrict__ b5,
                            const float* __restrict__ w0, const float* __restrict__ b0,
                            unsigned short* __restrict__ frags,
                            float* __restrict__ bsc,
                            float* __restrict__ w0s, float* __restrict__ b0s) {
    int s = blockIdx.x, lane = threadIdx.x;
    if (s < 18) {
        const float* Ws[5] = {w1, w2, w3, w4, w5};
        const float* W = Ws[s < 16 ? (s >> 2) : 4];
        int u = (s < 16) ? ((s >> 1) & 1) : 0;
        int hsel = s & 1;
        int m = (lane & 15) + 16 * u;
        int k0 = (lane >> 4) << 3;
        for (int j = 0; j < 8; ++j) {
            float v = W[m * 32 + sigma(k0 + j)] * SINSCALE;
            HU hi; hi.h = __float2half(v);           // RNE
            HU outv;
            if (hsel) outv.h = __float2half(v - __half2float(hi.h));
            else      outv = hi;
            frags[(s * 64 + lane) * 8 + j] = outv.u;
        }
    } else {
        const float* Bs[4] = {b1, b2, b3, b4};
        for (int i = lane; i < 128; i += 64) bsc[i] = Bs[i >> 5][i & 31] * SINSCALE;
        if (lane < 16) bsc[128 + lane] = b5[lane] * SINSCALE;
        // w0s[2p+e] = w0[2*sigma(p)+e]*S ; b0s[p] = b0[sigma(p)]*S
        {
            int p = lane >> 1, e = lane & 1;
            w0s[lane] = w0[2 * sigma(p) + e] * SINSCALE;
        }
        if (lane < 32) b0s[lane] = b0[sigma(lane)] * SINSCALE;
    }
}

__global__ __launch_bounds__(256, 4) void siren_mfma(
    const float* __restrict__ coords,
    const float* __restrict__ w0s, const float* __restrict__ b0s,
    const unsigned short* __restrict__ frags,
    const float* __restrict__ bsc,
    const float* __restrict__ wf, const float* __restrict__ bfin,
    float* __restrict__ out, int n) {
    __shared__ __align__(16) unsigned int lds[4][2][64 * RSD];  // 40960 B/block

    const int lane = (int)(threadIdx.x & 63);
    const int wv = (int)(threadIdx.x >> 6);

    const int q = lane >> 4;
    const int nl = lane & 15;

    const int pbase = blockIdx.x * 512 + wv * 128;

    // ---- L0: 2 -> 32 (sigma output order via permuted w0s/b0s), both groups ----
#pragma unroll
    for (int g = 0; g < 2; ++g) {
        unsigned int* A = &lds[wv][g][0];
        const int ptc = min(pbase + g * 64 + lane, n - 1);
        const float2 c = reinterpret_cast<const float2*>(coords)[ptc];
#pragma unroll
        for (int j0 = 0; j0 < 32; j0 += 8) {
            float s[8];
#pragma unroll
            for (int j = 0; j < 8; ++j) {
                float a = fmaf(w0s[2 * (j0 + j)], c.x,
                               fmaf(w0s[2 * (j0 + j) + 1], c.y, b0s[j0 + j]));
                s[j] = __builtin_amdgcn_sinf(a);
            }
            uint4 wb;
            wb.x = pk2(s[0], s[1]);
            wb.y = pk2(s[2], s[3]);
            wb.z = pk2(s[4], s[5]);
            wb.w = pk2(s[6], s[7]);
            *reinterpret_cast<uint4*>(&A[lane * RSD + j0 / 2]) = wb;
        }
    }

    const uint4* F = reinterpret_cast<const uint4*>(frags);

    // ---- middle layers 1..4: 32 -> 32, groups staggered ----
#pragma unroll 1
    for (int l = 0; l < 4; ++l) {
        S16 Ah0, Al0, Ah1, Al1;
        Ah0.u4 = F[(l * 4 + 0) * 64 + lane];
        Al0.u4 = F[(l * 4 + 1) * 64 + lane];
        Ah1.u4 = F[(l * 4 + 2) * 64 + lane];
        Al1.u4 = F[(l * 4 + 3) * 64 + lane];
        const float4 bq0 = *reinterpret_cast<const float4*>(&bsc[l * 32 + 4 * q]);
        const float4 bq1 = *reinterpret_cast<const float4*>(&bsc[l * 32 + 16 + 4 * q]);
        const f32x4 bv0 = {bq0.x, bq0.y, bq0.z, bq0.w};
        const f32x4 bv1 = {bq1.x, bq1.y, bq1.z, bq1.w};

#pragma unroll
        for (int g = 0; g < 2; ++g) {
            unsigned int* A = &lds[wv][g][0];
            f32x4 acc[4][2];
#pragma unroll
            for (int t = 0; t < 4; ++t) {
                S16 Bt;
                Bt.u4 = *reinterpret_cast<const uint4*>(&A[(16 * t + nl) * RSD + 4 * q]);
                f32x4 c0 = __builtin_amdgcn_mfma_f32_16x16x32_f16(Ah0.h, Bt.h, bv0, 0, 0, 0);
                c0 = __builtin_amdgcn_mfma_f32_16x16x32_f16(Al0.h, Bt.h, c0, 0, 0, 0);
                f32x4 c1 = __builtin_amdgcn_mfma_f32_16x16x32_f16(Ah1.h, Bt.h, bv1, 0, 0, 0);
                c1 = __builtin_amdgcn_mfma_f32_16x16x32_f16(Al1.h, Bt.h, c1, 0, 0, 0);
                acc[t][0] = c0;
                acc[t][1] = c1;
            }
            // sin + pack; lane's 8 outputs (u,r) land at k-slots 8q..8q+7 -> one b128
#pragma unroll
            for (int t = 0; t < 4; ++t) {
                uint4 wb;
                wb.x = pk2(__builtin_amdgcn_sinf(acc[t][0][0]),
                           __builtin_amdgcn_sinf(acc[t][0][1]));
                wb.y = pk2(__builtin_amdgcn_sinf(acc[t][0][2]),
                           __builtin_amdgcn_sinf(acc[t][0][3]));
                wb.z = pk2(__builtin_amdgcn_sinf(acc[t][1][0]),
                           __builtin_amdgcn_sinf(acc[t][1][1]));
                wb.w = pk2(__builtin_amdgcn_sinf(acc[t][1][2]),
                           __builtin_amdgcn_sinf(acc[t][1][3]));
                *reinterpret_cast<uint4*>(&A[(16 * t + nl) * RSD + 4 * q]) = wb;
            }
        }
    }

    // ---- L5: 32 -> 16 (k uses sigma; outputs natural order, raw f32) ----
    {
        S16 Ah5, Al5;
        Ah5.u4 = F[16 * 64 + lane];
        Al5.u4 = F[17 * 64 + lane];
        const float4 bq5 = *reinterpret_cast<const float4*>(&bsc[128 + 4 * q]);
        const f32x4 bv5 = {bq5.x, bq5.y, bq5.z, bq5.w};
#pragma unroll
        for (int g = 0; g < 2; ++g) {
            unsigned int* A = &lds[wv][g][0];
            f32x4 a5[4];
#pragma unroll
            for (int t = 0; t < 4; ++t) {
                S16 Bt;
                Bt.u4 = *reinterpret_cast<const uint4*>(&A[(16 * t + nl) * RSD + 4 * q]);
                f32x4 c = __builtin_amdgcn_mfma_f32_16x16x32_f16(Ah5.h, Bt.h, bv5, 0, 0, 0);
                c = __builtin_amdgcn_mfma_f32_16x16x32_f16(Al5.h, Bt.h, c, 0, 0, 0);
                a5[t] = c;
            }
#pragma unroll
            for (int t = 0; t < 4; ++t) {
                uint4 wb;
                wb.x = __float_as_uint(__builtin_amdgcn_sinf(a5[t][0]));
                wb.y = __float_as_uint(__builtin_amdgcn_sinf(a5[t][1]));
                wb.z = __float_as_uint(__builtin_amdgcn_sinf(a5[t][2]));
                wb.w = __float_as_uint(__builtin_amdgcn_sinf(a5[t][3]));
                *reinterpret_cast<uint4*>(&A[(16 * t + nl) * RSD + 4 * q]) = wb;
            }
        }
    }

    // ---- final: 16 -> 3 + sigmoid, point-per-lane f32 readback, both groups ----
#pragma unroll
    for (int g = 0; g < 2; ++g) {
        unsigned int* A = &lds[wv][g][0];
        const int pt = pbase + g * 64 + lane;
        float hv[16];
        const uint4* hr = reinterpret_cast<const uint4*>(&A[lane * RSD]);
#pragma unroll
        for (int cch = 0; cch < 4; ++cch) {
            uint4 v = hr[cch];
            hv[4 * cch + 0] = __uint_as_float(v.x);
            hv[4 * cch + 1] = __uint_as_float(v.y);
            hv[4 * cch + 2] = __uint_as_float(v.z);
            hv[4 * cch + 3] = __uint_as_float(v.w);
        }
        float o[3];
#pragma unroll
        for (int c = 0; c < 3; ++c) {
            float a = bfin[c];
#pragma unroll
            for (int k = 0; k < 16; ++k) a = fmaf(wf[c * 16 + k], hv[k], a);
            o[c] = fast_sigmoid(a);
        }
        if (pt < n) {
            out[pt * 3 + 0] = o[0];
            out[pt * 3 + 1] = o[1];
            out[pt * 3 + 2] = o[2];
        }
    }
}

extern "C" void kernel_launch(void* const* d_in, const int* in_sizes, int n_in,
                              void* d_out, int out_size, void* d_ws, size_t ws_size,
                              hipStream_t stream) {
    const float* coords = (const float*)d_in[0];
    const float* w0 = (const float*)d_in[1];
    const float* b0 = (const float*)d_in[2];
    const float* w1 = (const float*)d_in[3];
    const float* b1 = (const float*)d_in[4];
    const float* w2 = (const float*)d_in[5];
    const float* b2 = (const float*)d_in[6];
    const float* w3 = (const float*)d_in[7];
    const float* b3 = (const float*)d_in[8];
    const float* w4 = (const float*)d_in[9];
    const float* b4 = (const float*)d_in[10];
    const float* w5 = (const float*)d_in[11];
    const float* b5 = (const float*)d_in[12];
    const float* wf = (const float*)d_in[13];
    const float* bf = (const float*)d_in[14];
    float* out = (float*)d_out;

    // ws: frags 18*64*8 f16 = 18432 B [0,18432); bsc(144f) [18432,19008);
    //     w0s(64f) [19008,19264); b0s(32f) [19264,19392)
    unsigned short* frags = (unsigned short*)d_ws;
    float* bsc = (float*)((char*)d_ws + 18432);
    float* w0s = (float*)((char*)d_ws + 19008);
    float* b0s = (float*)((char*)d_ws + 19264);

    const int n = in_sizes[0] / 2;

    prep_kernel<<<19, 64, 0, stream>>>(w1, w2, w3, w4, w5, b1, b2, b3, b4, b5,
                                       w0, b0, frags, bsc, w0s, b0s);
    siren_mfma<<<(n + 511) / 512, 256, 0, stream>>>(
        coords, w0s, b0s, frags, bsc, wf, bf, out, n);
}

// Round 8
// 143.702 us; speedup vs baseline: 1.0324x; 1.0324x over previous
//
#include <hip/hip_runtime.h>
#include <hip/hip_fp16.h>

// SIREN, fully register-resident MFMA pipeline. ZERO LDS storage.
// A=weights / B=activations: D[16 feat x 16 pt] = W[16,32] * X[32,16 pt].
// Key identity: with k-order permutation sigma(p)=16*((p>>2)&1)+4*(p>>3)+(p&3)
// applied to all weight A-fragments, a lane's packed sin outputs
// {pk2(c0[0],c0[1]), pk2(c0[2],c0[3]), pk2(c1[0],c1[1]), pk2(c1[2],c1[3])}
// ARE the next layer's B-fragment for the same m-tile (verified: slot 8q+j ->
// feature 16*(j>>2)+4q+(j&3) = this lane's own outputs). So layers 1..5 never
// touch memory: MFMA -> v_sin -> v_cvt_pkrtz -> MFMA, 4 independent t-chains.
// L0 computed directly in B-frag format (w0s/b0s sigma-permuted by prep).
// Final 16->3: per-lane partials + shfl_xor(16,32) butterfly, no LDS.
// Weight hi/lo f16 split (2 chained MFMAs) keeps weights exact; only activation
// f16 quantization remains. 30/(2pi) folded into weights/biases at prep.

#define SINSCALE 4.774648292756860f   // 30/(2*pi)

typedef __attribute__((ext_vector_type(8))) _Float16 half8;
typedef __attribute__((ext_vector_type(2))) __fp16 fp16x2;
typedef __attribute__((ext_vector_type(4))) float f32x4;

union S16 { uint4 u4; half8 h; };
union PK { fp16x2 h2; unsigned int u; };
union HU { __half h; unsigned short u; };

__device__ __forceinline__ float fast_sigmoid(float t) {
    float e = __builtin_amdgcn_exp2f(t * -1.4426950408889634f);
    return 1.0f / (1.0f + e);
}

__device__ __forceinline__ unsigned int pk2(float a, float b) {
    PK p; p.h2 = __builtin_amdgcn_cvt_pkrtz(a, b);
    return p.u;
}

// k-slot p holds activation of physical feature sigma(p)
__device__ __forceinline__ int sigma(int p) {
    return 16 * ((p >> 2) & 1) + 4 * (p >> 3) + (p & 3);
}

// ---- prep: 19 blocks x 64 lanes (same layout as R7) ----
// A-frag (16x16x32 f16): lane holds A[m=lane&15][p=(lane>>4)*8+j], j=0..7,
// value = split(W[row][sigma(p)] * SINSCALE).
// frag s<16: l=s>>2 (w1..w4), u=(s>>1)&1 (rows 16u+m), h=s&1 (0=hi,1=lo).
// s=16+h: w5 (u=0). Block 18: bsc biases; w0s/b0s in sigma slot order.
__global__ void prep_kernel(const float* __restrict__ w1, const float* __restrict__ w2,
                            const float* __restrict__ w3, const float* __restrict__ w4,
                            const float* __restrict__ w5,
                            const float* __restrict__ b1, const float* __restrict__ b2,
                            const float* __restrict__ b3, const float* __restrict__ b4,
                            const float* __restrict__ b5,
                            const float* __restrict__ w0, const float* __restrict__ b0,
                            unsigned short* __restrict__ frags,
                            float* __restrict__ bsc,
                            float* __restrict__ w0s, float* __restrict__ b0s) {
    int s = blockIdx.x, lane = threadIdx.x;
    if (s < 18) {
        const float* Ws[5] = {w1, w2, w3, w4, w5};
        const float* W = Ws[s < 16 ? (s >> 2) : 4];
        int u = (s < 16) ? ((s >> 1) & 1) : 0;
        int hsel = s & 1;
        int m = (lane & 15) + 16 * u;
        int k0 = (lane >> 4) << 3;
        for (int j = 0; j < 8; ++j) {
            float v = W[m * 32 + sigma(k0 + j)] * SINSCALE;
            HU hi; hi.h = __float2half(v);           // RNE
            HU outv;
            if (hsel) outv.h = __float2half(v - __half2float(hi.h));
            else      outv = hi;
            frags[(s * 64 + lane) * 8 + j] = outv.u;
        }
    } else {
        const float* Bs[4] = {b1, b2, b3, b4};
        for (int i = lane; i < 128; i += 64) bsc[i] = Bs[i >> 5][i & 31] * SINSCALE;
        if (lane < 16) bsc[128 + lane] = b5[lane] * SINSCALE;
        {
            int p = lane >> 1, e = lane & 1;
            w0s[lane] = w0[2 * sigma(p) + e] * SINSCALE;   // w0s[2p+e]
        }
        if (lane < 32) b0s[lane] = b0[sigma(lane)] * SINSCALE;
    }
}

__global__ __launch_bounds__(256, 6) void siren_mfma(
    const float* __restrict__ coords,
    const float* __restrict__ w0s, const float* __restrict__ b0s,
    const unsigned short* __restrict__ frags,
    const float* __restrict__ bsc,
    const float* __restrict__ wf, const float* __restrict__ bfin,
    float* __restrict__ out, int n) {
    const int lane = (int)(threadIdx.x & 63);
    const int q = lane >> 4;
    const int nl = lane & 15;
    const int pbase = blockIdx.x * 256 + (int)(threadIdx.x >> 6) * 64;

    // ---- L0: 2 -> 32, computed directly in B-frag format ----
    // lane (q,nl): slots p=8q+j hold sin of feature sigma(p) of point 16t+nl.
    float cx[4], cy[4];
#pragma unroll
    for (int t = 0; t < 4; ++t) {
        int ptc = min(pbase + 16 * t + nl, n - 1);
        float2 c = reinterpret_cast<const float2*>(coords)[ptc];
        cx[t] = c.x;
        cy[t] = c.y;
    }
    const float4* W0 = reinterpret_cast<const float4*>(w0s + 16 * q);  // w0s[16q..16q+16)
    float4 wva = W0[0], wvb = W0[1], wvc = W0[2], wvd = W0[3];
    const float4* B0 = reinterpret_cast<const float4*>(b0s + 8 * q);
    float4 bva = B0[0], bvb = B0[1];
    float wx[8] = {wva.x, wva.z, wvb.x, wvb.z, wvc.x, wvc.z, wvd.x, wvd.z};
    float wy[8] = {wva.y, wva.w, wvb.y, wvb.w, wvc.y, wvc.w, wvd.y, wvd.w};
    float bb[8] = {bva.x, bva.y, bva.z, bva.w, bvb.x, bvb.y, bvb.z, bvb.w};

    uint4 Bt[4];
#pragma unroll
    for (int t = 0; t < 4; ++t) {
        float s[8];
#pragma unroll
        for (int j = 0; j < 8; ++j)
            s[j] = __builtin_amdgcn_sinf(fmaf(wx[j], cx[t], fmaf(wy[j], cy[t], bb[j])));
        Bt[t].x = pk2(s[0], s[1]);
        Bt[t].y = pk2(s[2], s[3]);
        Bt[t].z = pk2(s[4], s[5]);
        Bt[t].w = pk2(s[6], s[7]);
    }

    const uint4* F = reinterpret_cast<const uint4*>(frags);

    // ---- middle layers 1..4: 32 -> 32, fully in registers ----
#pragma unroll 1
    for (int l = 0; l < 4; ++l) {
        S16 Ah0, Al0, Ah1, Al1;
        Ah0.u4 = F[(l * 4 + 0) * 64 + lane];
        Al0.u4 = F[(l * 4 + 1) * 64 + lane];
        Ah1.u4 = F[(l * 4 + 2) * 64 + lane];
        Al1.u4 = F[(l * 4 + 3) * 64 + lane];
        const float4 bq0 = *reinterpret_cast<const float4*>(&bsc[l * 32 + 4 * q]);
        const float4 bq1 = *reinterpret_cast<const float4*>(&bsc[l * 32 + 16 + 4 * q]);
        const f32x4 bv0 = {bq0.x, bq0.y, bq0.z, bq0.w};
        const f32x4 bv1 = {bq1.x, bq1.y, bq1.z, bq1.w};
#pragma unroll
        for (int t = 0; t < 4; ++t) {
            S16 B;
            B.u4 = Bt[t];
            f32x4 c0 = __builtin_amdgcn_mfma_f32_16x16x32_f16(Ah0.h, B.h, bv0, 0, 0, 0);
            c0 = __builtin_amdgcn_mfma_f32_16x16x32_f16(Al0.h, B.h, c0, 0, 0, 0);
            f32x4 c1 = __builtin_amdgcn_mfma_f32_16x16x32_f16(Ah1.h, B.h, bv1, 0, 0, 0);
            c1 = __builtin_amdgcn_mfma_f32_16x16x32_f16(Al1.h, B.h, c1, 0, 0, 0);
            Bt[t].x = pk2(__builtin_amdgcn_sinf(c0[0]), __builtin_amdgcn_sinf(c0[1]));
            Bt[t].y = pk2(__builtin_amdgcn_sinf(c0[2]), __builtin_amdgcn_sinf(c0[3]));
            Bt[t].z = pk2(__builtin_amdgcn_sinf(c1[0]), __builtin_amdgcn_sinf(c1[1]));
            Bt[t].w = pk2(__builtin_amdgcn_sinf(c1[2]), __builtin_amdgcn_sinf(c1[3]));
        }
    }

    // ---- L5 (32->16) + final (16->3): registers + shfl butterfly ----
    {
        S16 Ah5, Al5;
        Ah5.u4 = F[16 * 64 + lane];
        Al5.u4 = F[17 * 64 + lane];
        const float4 bq5 = *reinterpret_cast<const float4*>(&bsc[128 + 4 * q]);
        const f32x4 bv5 = {bq5.x, bq5.y, bq5.z, bq5.w};
        float4 wfl[3];
#pragma unroll
        for (int c = 0; c < 3; ++c)
            wfl[c] = *reinterpret_cast<const float4*>(&wf[c * 16 + 4 * q]);

        float red[4][3];
#pragma unroll
        for (int t = 0; t < 4; ++t) {
            S16 B;
            B.u4 = Bt[t];
            f32x4 c5 = __builtin_amdgcn_mfma_f32_16x16x32_f16(Ah5.h, B.h, bv5, 0, 0, 0);
            c5 = __builtin_amdgcn_mfma_f32_16x16x32_f16(Al5.h, B.h, c5, 0, 0, 0);
            float h0 = __builtin_amdgcn_sinf(c5[0]);
            float h1 = __builtin_amdgcn_sinf(c5[1]);
            float h2 = __builtin_amdgcn_sinf(c5[2]);
            float h3 = __builtin_amdgcn_sinf(c5[3]);
#pragma unroll
            for (int c = 0; c < 3; ++c)
                red[t][c] = fmaf(wfl[c].x, h0, fmaf(wfl[c].y, h1,
                            fmaf(wfl[c].z, h2, wfl[c].w * h3)));
        }
        // butterfly over the 4 q-lanes sharing a point column
#pragma unroll
        for (int t = 0; t < 4; ++t)
#pragma unroll
            for (int c = 0; c < 3; ++c) {
                float v = red[t][c];
                v += __shfl_xor(v, 16, 64);
                v += __shfl_xor(v, 32, 64);
                red[t][c] = v;
            }
        // lane handles point 16q+nl (t=q), select via cndmask chain
        float o[3];
#pragma unroll
        for (int c = 0; c < 3; ++c) {
            float v01 = (q & 1) ? red[1][c] : red[0][c];
            float v23 = (q & 1) ? red[3][c] : red[2][c];
            float v = (q & 2) ? v23 : v01;
            o[c] = fast_sigmoid(v + bfin[c]);
        }
        const int pq = pbase + 16 * q + nl;
        if (pq < n) {
            out[3 * pq + 0] = o[0];
            out[3 * pq + 1] = o[1];
            out[3 * pq + 2] = o[2];
        }
    }
}

extern "C" void kernel_launch(void* const* d_in, const int* in_sizes, int n_in,
                              void* d_out, int out_size, void* d_ws, size_t ws_size,
                              hipStream_t stream) {
    const float* coords = (const float*)d_in[0];
    const float* w0 = (const float*)d_in[1];
    const float* b0 = (const float*)d_in[2];
    const float* w1 = (const float*)d_in[3];
    const float* b1 = (const float*)d_in[4];
    const float* w2 = (const float*)d_in[5];
    const float* b2 = (const float*)d_in[6];
    const float* w3 = (const float*)d_in[7];
    const float* b3 = (const float*)d_in[8];
    const float* w4 = (const float*)d_in[9];
    const float* b4 = (const float*)d_in[10];
    const float* w5 = (const float*)d_in[11];
    const float* b5 = (const float*)d_in[12];
    const float* wf = (const float*)d_in[13];
    const float* bf = (const float*)d_in[14];
    float* out = (float*)d_out;

    // ws: frags 18*64*8 f16 = 18432 B [0,18432); bsc(144f) [18432,19008);
    //     w0s(64f) [19008,19264); b0s(32f) [19264,19392)
    unsigned short* frags = (unsigned short*)d_ws;
    float* bsc = (float*)((char*)d_ws + 18432);
    float* w0s = (float*)((char*)d_ws + 19008);
    float* b0s = (float*)((char*)d_ws + 19264);

    const int n = in_sizes[0] / 2;

    prep_kernel<<<19, 64, 0, stream>>>(w1, w2, w3, w4, w5, b1, b2, b3, b4, b5,
                                       w0, b0, frags, bsc, w0s, b0s);
    siren_mfma<<<(n + 255) / 256, 256, 0, stream>>>(
        coords, w0s, b0s, frags, bsc, wf, bf, out, n);
}

// Round 10
// 142.611 us; speedup vs baseline: 1.0403x; 1.0077x over previous
//
#include <hip/hip_runtime.h>
#include <hip/hip_fp16.h>

// SIREN, fully register-resident MFMA pipeline, 128 points/wave (8 m-tiles).
// A=weights / B=activations: D[16 feat x 16 pt] = W[16,32] * X[32,16 pt].
// sigma(p)=16*((p>>2)&1)+4*(p>>3)+(p&3) k-permutation makes each lane's packed
// sin outputs BE the next layer's B-fragment (no LDS, no shuffles in the loop).
// 8 independent per-tile chains hide MFMA->sin->pack latency; the 4-layer loop
// is fully unrolled so weight-fragment loads software-pipeline across layers.
// Weight hi/lo f16 split (2 chained MFMAs) keeps weights exact; only activation
// f16 quantization remains. 30/(2pi) folded into weights/biases at prep.
// R9 bug fixed: block covers 4 waves * 128 = 512 points -> pbase stride 512.

#define SINSCALE 4.774648292756860f   // 30/(2*pi)

typedef __attribute__((ext_vector_type(8))) _Float16 half8;
typedef __attribute__((ext_vector_type(2))) __fp16 fp16x2;
typedef __attribute__((ext_vector_type(4))) float f32x4;

union S16 { uint4 u4; half8 h; };
union PK { fp16x2 h2; unsigned int u; };
union HU { __half h; unsigned short u; };

__device__ __forceinline__ float fast_sigmoid(float t) {
    float e = __builtin_amdgcn_exp2f(t * -1.4426950408889634f);
    return 1.0f / (1.0f + e);
}

__device__ __forceinline__ unsigned int pk2(float a, float b) {
    PK p; p.h2 = __builtin_amdgcn_cvt_pkrtz(a, b);
    return p.u;
}

// k-slot p holds activation of physical feature sigma(p)
__device__ __forceinline__ int sigma(int p) {
    return 16 * ((p >> 2) & 1) + 4 * (p >> 3) + (p & 3);
}

// ---- prep: 19 blocks x 64 lanes (unchanged layout) ----
__global__ void prep_kernel(const float* __restrict__ w1, const float* __restrict__ w2,
                            const float* __restrict__ w3, const float* __restrict__ w4,
                            const float* __restrict__ w5,
                            const float* __restrict__ b1, const float* __restrict__ b2,
                            const float* __restrict__ b3, const float* __restrict__ b4,
                            const float* __restrict__ b5,
                            const float* __restrict__ w0, const float* __restrict__ b0,
                            unsigned short* __restrict__ frags,
                            float* __restrict__ bsc,
                            float* __restrict__ w0s, float* __restrict__ b0s) {
    int s = blockIdx.x, lane = threadIdx.x;
    if (s < 18) {
        const float* Ws[5] = {w1, w2, w3, w4, w5};
        const float* W = Ws[s < 16 ? (s >> 2) : 4];
        int u = (s < 16) ? ((s >> 1) & 1) : 0;
        int hsel = s & 1;
        int m = (lane & 15) + 16 * u;
        int k0 = (lane >> 4) << 3;
        for (int j = 0; j < 8; ++j) {
            float v = W[m * 32 + sigma(k0 + j)] * SINSCALE;
            HU hi; hi.h = __float2half(v);           // RNE
            HU outv;
            if (hsel) outv.h = __float2half(v - __half2float(hi.h));
            else      outv = hi;
            frags[(s * 64 + lane) * 8 + j] = outv.u;
        }
    } else {
        const float* Bs[4] = {b1, b2, b3, b4};
        for (int i = lane; i < 128; i += 64) bsc[i] = Bs[i >> 5][i & 31] * SINSCALE;
        if (lane < 16) bsc[128 + lane] = b5[lane] * SINSCALE;
        {
            int p = lane >> 1, e = lane & 1;
            w0s[lane] = w0[2 * sigma(p) + e] * SINSCALE;   // w0s[2p+e]
        }
        if (lane < 32) b0s[lane] = b0[sigma(lane)] * SINSCALE;
    }
}

__global__ __launch_bounds__(256, 4) void siren_mfma(
    const float* __restrict__ coords,
    const float* __restrict__ w0s, const float* __restrict__ b0s,
    const unsigned short* __restrict__ frags,
    const float* __restrict__ bsc,
    const float* __restrict__ wf, const float* __restrict__ bfin,
    float* __restrict__ out, int n) {
    const int lane = (int)(threadIdx.x & 63);
    const int q = lane >> 4;
    const int nl = lane & 15;
    const int pbase = blockIdx.x * 512 + (int)(threadIdx.x >> 6) * 128;

    // ---- L0: 2 -> 32 directly in B-frag format, 8 tiles ----
    const float4* W0 = reinterpret_cast<const float4*>(w0s + 16 * q);
    float4 wva = W0[0], wvb = W0[1], wvc = W0[2], wvd = W0[3];
    const float4* B0 = reinterpret_cast<const float4*>(b0s + 8 * q);
    float4 bva = B0[0], bvb = B0[1];
    float wx[8] = {wva.x, wva.z, wvb.x, wvb.z, wvc.x, wvc.z, wvd.x, wvd.z};
    float wy[8] = {wva.y, wva.w, wvb.y, wvb.w, wvc.y, wvc.w, wvd.y, wvd.w};
    float bb[8] = {bva.x, bva.y, bva.z, bva.w, bvb.x, bvb.y, bvb.z, bvb.w};

    uint4 Bt[8];
#pragma unroll
    for (int t = 0; t < 8; ++t) {
        int ptc = min(pbase + 16 * t + nl, n - 1);
        float2 c = reinterpret_cast<const float2*>(coords)[ptc];
        float s[8];
#pragma unroll
        for (int j = 0; j < 8; ++j)
            s[j] = __builtin_amdgcn_sinf(fmaf(wx[j], c.x, fmaf(wy[j], c.y, bb[j])));
        Bt[t].x = pk2(s[0], s[1]);
        Bt[t].y = pk2(s[2], s[3]);
        Bt[t].z = pk2(s[4], s[5]);
        Bt[t].w = pk2(s[6], s[7]);
    }

    const uint4* F = reinterpret_cast<const uint4*>(frags);

    // ---- middle layers 1..4 (fully unrolled: frag loads pipeline across layers) ----
#pragma unroll
    for (int l = 0; l < 4; ++l) {
        S16 Ah0, Al0, Ah1, Al1;
        Ah0.u4 = F[(l * 4 + 0) * 64 + lane];
        Al0.u4 = F[(l * 4 + 1) * 64 + lane];
        Ah1.u4 = F[(l * 4 + 2) * 64 + lane];
        Al1.u4 = F[(l * 4 + 3) * 64 + lane];
        const float4 bq0 = *reinterpret_cast<const float4*>(&bsc[l * 32 + 4 * q]);
        const float4 bq1 = *reinterpret_cast<const float4*>(&bsc[l * 32 + 16 + 4 * q]);
        const f32x4 bv0 = {bq0.x, bq0.y, bq0.z, bq0.w};
        const f32x4 bv1 = {bq1.x, bq1.y, bq1.z, bq1.w};
#pragma unroll
        for (int t = 0; t < 8; ++t) {
            S16 B;
            B.u4 = Bt[t];
            f32x4 c0 = __builtin_amdgcn_mfma_f32_16x16x32_f16(Ah0.h, B.h, bv0, 0, 0, 0);
            c0 = __builtin_amdgcn_mfma_f32_16x16x32_f16(Al0.h, B.h, c0, 0, 0, 0);
            f32x4 c1 = __builtin_amdgcn_mfma_f32_16x16x32_f16(Ah1.h, B.h, bv1, 0, 0, 0);
            c1 = __builtin_amdgcn_mfma_f32_16x16x32_f16(Al1.h, B.h, c1, 0, 0, 0);
            Bt[t].x = pk2(__builtin_amdgcn_sinf(c0[0]), __builtin_amdgcn_sinf(c0[1]));
            Bt[t].y = pk2(__builtin_amdgcn_sinf(c0[2]), __builtin_amdgcn_sinf(c0[3]));
            Bt[t].z = pk2(__builtin_amdgcn_sinf(c1[0]), __builtin_amdgcn_sinf(c1[1]));
            Bt[t].w = pk2(__builtin_amdgcn_sinf(c1[2]), __builtin_amdgcn_sinf(c1[3]));
        }
    }

    // ---- L5 (32->16) + final (16->3): registers + shfl butterfly ----
    {
        S16 Ah5, Al5;
        Ah5.u4 = F[16 * 64 + lane];
        Al5.u4 = F[17 * 64 + lane];
        const float4 bq5 = *reinterpret_cast<const float4*>(&bsc[128 + 4 * q]);
        const f32x4 bv5 = {bq5.x, bq5.y, bq5.z, bq5.w};
        float4 wfl[3];
#pragma unroll
        for (int c = 0; c < 3; ++c)
            wfl[c] = *reinterpret_cast<const float4*>(&wf[c * 16 + 4 * q]);

        float red[8][3];
#pragma unroll
        for (int t = 0; t < 8; ++t) {
            S16 B;
            B.u4 = Bt[t];
            f32x4 c5 = __builtin_amdgcn_mfma_f32_16x16x32_f16(Ah5.h, B.h, bv5, 0, 0, 0);
            c5 = __builtin_amdgcn_mfma_f32_16x16x32_f16(Al5.h, B.h, c5, 0, 0, 0);
            float h0 = __builtin_amdgcn_sinf(c5[0]);
            float h1 = __builtin_amdgcn_sinf(c5[1]);
            float h2 = __builtin_amdgcn_sinf(c5[2]);
            float h3 = __builtin_amdgcn_sinf(c5[3]);
#pragma unroll
            for (int c = 0; c < 3; ++c)
                red[t][c] = fmaf(wfl[c].x, h0, fmaf(wfl[c].y, h1,
                            fmaf(wfl[c].z, h2, wfl[c].w * h3)));
        }
        // butterfly over the 4 q-lanes sharing a point column
#pragma unroll
        for (int t = 0; t < 8; ++t)
#pragma unroll
            for (int c = 0; c < 3; ++c) {
                float v = red[t][c];
                v += __shfl_xor(v, 16, 64);
                v += __shfl_xor(v, 32, 64);
                red[t][c] = v;
            }
        // lane outputs two points: t=q (pts 0..63) and t=4+q (pts 64..127)
        float o0[3], o1[3];
#pragma unroll
        for (int c = 0; c < 3; ++c) {
            float v01 = (q & 1) ? red[1][c] : red[0][c];
            float v23 = (q & 1) ? red[3][c] : red[2][c];
            o0[c] = fast_sigmoid(((q & 2) ? v23 : v01) + bfin[c]);
            float w01 = (q & 1) ? red[5][c] : red[4][c];
            float w23 = (q & 1) ? red[7][c] : red[6][c];
            o1[c] = fast_sigmoid(((q & 2) ? w23 : w01) + bfin[c]);
        }
        const int p0 = pbase + 16 * q + nl;
        const int p1 = p0 + 64;
        if (p0 < n) {
            out[3 * p0 + 0] = o0[0];
            out[3 * p0 + 1] = o0[1];
            out[3 * p0 + 2] = o0[2];
        }
        if (p1 < n) {
            out[3 * p1 + 0] = o1[0];
            out[3 * p1 + 1] = o1[1];
            out[3 * p1 + 2] = o1[2];
        }
    }
}

extern "C" void kernel_launch(void* const* d_in, const int* in_sizes, int n_in,
                              void* d_out, int out_size, void* d_ws, size_t ws_size,
                              hipStream_t stream) {
    const float* coords = (const float*)d_in[0];
    const float* w0 = (const float*)d_in[1];
    const float* b0 = (const float*)d_in[2];
    const float* w1 = (const float*)d_in[3];
    const float* b1 = (const float*)d_in[4];
    const float* w2 = (const float*)d_in[5];
    const float* b2 = (const float*)d_in[6];
    const float* w3 = (const float*)d_in[7];
    const float* b3 = (const float*)d_in[8];
    const float* w4 = (const float*)d_in[9];
    const float* b4 = (const float*)d_in[10];
    const float* w5 = (const float*)d_in[11];
    const float* b5 = (const float*)d_in[12];
    const float* wf = (const float*)d_in[13];
    const float* bf = (const float*)d_in[14];
    float* out = (float*)d_out;

    // ws: frags 18*64*8 f16 = 18432 B [0,18432); bsc(144f) [18432,19008);
    //     w0s(64f) [19008,19264); b0s(32f) [19264,19392)
    unsigned short* frags = (unsigned short*)d_ws;
    float* bsc = (float*)((char*)d_ws + 18432);
    float* w0s = (float*)((char*)d_ws + 19008);
    float* b0s = (float*)((char*)d_ws + 19264);

    const int n = in_sizes[0] / 2;

    prep_kernel<<<19, 64, 0, stream>>>(w1, w2, w3, w4, w5, b1, b2, b3, b4, b5,
                                       w0, b0, frags, bsc, w0s, b0s);
    siren_mfma<<<(n + 511) / 512, 256, 0, stream>>>(
        coords, w0s, b0s, frags, bsc, wf, bf, out, n);
}

// Round 12
// 140.892 us; speedup vs baseline: 1.0530x; 1.0122x over previous
//
#include <hip/hip_runtime.h>
#include <hip/hip_fp16.h>

// SIREN, single fused kernel, fully register-resident, 128 points/wave.
// A=weights / B=activations: D[16 feat x 16 pt] = W[16,32] * X[32,16 pt].
// sigma(p)=16*((p>>2)&1)+4*(p>>3)+(p&3) k-permutation makes each lane's packed
// sin outputs BE the next layer's B-fragment (no LDS, no shuffles in the loop).
// sigma(8q+j) = {4q+j (j<4), 16+4q+(j-4) (j>=4)} -> a lane's A-fragment is two
// aligned float4 loads from the raw weight matrix, packed with v_cvt_pkrtz.
// So NO prep kernel and NO workspace: everything is built in-kernel from d_in.
// (R11 post-timing divergence = prep->main d_ws visibility hazard under graph
// replay; fusing removes the only cross-kernel state.)
// Weights single f16 (hi-only): adds ~2e-3 error, far under the 1.6e-2
// threshold. 30/(2pi) folded into weights/biases at load time.

#define SINSCALE 4.774648292756860f   // 30/(2*pi)

typedef __attribute__((ext_vector_type(8))) _Float16 half8;
typedef __attribute__((ext_vector_type(2))) __fp16 fp16x2;
typedef __attribute__((ext_vector_type(4))) float f32x4;

union S16 { uint4 u4; half8 h; };
union PK { fp16x2 h2; unsigned int u; };

__device__ __forceinline__ float fast_sigmoid(float t) {
    float e = __builtin_amdgcn_exp2f(t * -1.4426950408889634f);
    return 1.0f / (1.0f + e);
}

__device__ __forceinline__ unsigned int pk2(float a, float b) {
    PK p; p.h2 = __builtin_amdgcn_cvt_pkrtz(a, b);
    return p.u;
}

// Build the sigma-permuted A-fragment (hi f16, RTZ) for feature rows m:
// slots j=0..3 <- W[m][4q+j]*S, j=4..7 <- W[m][16+4q+(j-4)]*S.
__device__ __forceinline__ uint4 build_frag(const float* __restrict__ W, int m, int q) {
    const float4 fa = *reinterpret_cast<const float4*>(&W[m * 32 + 4 * q]);
    const float4 fb = *reinterpret_cast<const float4*>(&W[m * 32 + 16 + 4 * q]);
    uint4 u;
    u.x = pk2(fa.x * SINSCALE, fa.y * SINSCALE);
    u.y = pk2(fa.z * SINSCALE, fa.w * SINSCALE);
    u.z = pk2(fb.x * SINSCALE, fb.y * SINSCALE);
    u.w = pk2(fb.z * SINSCALE, fb.w * SINSCALE);
    return u;
}

// Scaled bias vector for C/D rows 4q..4q+3 (+off)
__device__ __forceinline__ f32x4 bias_frag(const float* __restrict__ b, int off, int q) {
    const float4 t = *reinterpret_cast<const float4*>(&b[off + 4 * q]);
    f32x4 r = {t.x * SINSCALE, t.y * SINSCALE, t.z * SINSCALE, t.w * SINSCALE};
    return r;
}

__global__ __launch_bounds__(256, 4) void siren_mfma(
    const float* __restrict__ coords,
    const float* __restrict__ w0, const float* __restrict__ b0,
    const float* __restrict__ w1, const float* __restrict__ b1,
    const float* __restrict__ w2, const float* __restrict__ b2,
    const float* __restrict__ w3, const float* __restrict__ b3,
    const float* __restrict__ w4, const float* __restrict__ b4,
    const float* __restrict__ w5, const float* __restrict__ b5,
    const float* __restrict__ wf, const float* __restrict__ bfin,
    float* __restrict__ out, int n) {
    const int lane = (int)(threadIdx.x & 63);
    const int q = lane >> 4;
    const int nl = lane & 15;
    const int pbase = blockIdx.x * 512 + (int)(threadIdx.x >> 6) * 128;

    // ---- weight fragments for layers 1..5, built from raw matrices ----
    uint4 Af[4][2];
    Af[0][0] = build_frag(w1, nl, q);  Af[0][1] = build_frag(w1, 16 + nl, q);
    Af[1][0] = build_frag(w2, nl, q);  Af[1][1] = build_frag(w2, 16 + nl, q);
    Af[2][0] = build_frag(w3, nl, q);  Af[2][1] = build_frag(w3, 16 + nl, q);
    Af[3][0] = build_frag(w4, nl, q);  Af[3][1] = build_frag(w4, 16 + nl, q);
    const uint4 Af5 = build_frag(w5, nl, q);

    // ---- L0: 2 -> 32 directly in B-frag format (features sigma(8q+j)) ----
    const float4 wa = *reinterpret_cast<const float4*>(&w0[8 * q]);
    const float4 wb = *reinterpret_cast<const float4*>(&w0[8 * q + 4]);
    const float4 wc = *reinterpret_cast<const float4*>(&w0[32 + 8 * q]);
    const float4 wd = *reinterpret_cast<const float4*>(&w0[32 + 8 * q + 4]);
    const float4 ba = *reinterpret_cast<const float4*>(&b0[4 * q]);
    const float4 bc = *reinterpret_cast<const float4*>(&b0[16 + 4 * q]);
    float wxs[8] = {wa.x, wa.z, wb.x, wb.z, wc.x, wc.z, wd.x, wd.z};
    float wys[8] = {wa.y, wa.w, wb.y, wb.w, wc.y, wc.w, wd.y, wd.w};
    float bbs[8] = {ba.x, ba.y, ba.z, ba.w, bc.x, bc.y, bc.z, bc.w};
#pragma unroll
    for (int j = 0; j < 8; ++j) {
        wxs[j] *= SINSCALE;
        wys[j] *= SINSCALE;
        bbs[j] *= SINSCALE;
    }

    uint4 Bt[8];
#pragma unroll
    for (int t = 0; t < 8; ++t) {
        int ptc = min(pbase + 16 * t + nl, n - 1);
        float2 c = reinterpret_cast<const float2*>(coords)[ptc];
        float s[8];
#pragma unroll
        for (int j = 0; j < 8; ++j)
            s[j] = __builtin_amdgcn_sinf(fmaf(wxs[j], c.x, fmaf(wys[j], c.y, bbs[j])));
        Bt[t].x = pk2(s[0], s[1]);
        Bt[t].y = pk2(s[2], s[3]);
        Bt[t].z = pk2(s[4], s[5]);
        Bt[t].w = pk2(s[6], s[7]);
    }

    // ---- middle layers 1..4 (fully unrolled), hi-weights only ----
    const float* Bs[4] = {b1, b2, b3, b4};
#pragma unroll
    for (int l = 0; l < 4; ++l) {
        S16 Ah0, Ah1;
        Ah0.u4 = Af[l][0];
        Ah1.u4 = Af[l][1];
        const f32x4 bv0 = bias_frag(Bs[l], 0, q);
        const f32x4 bv1 = bias_frag(Bs[l], 16, q);
#pragma unroll
        for (int t = 0; t < 8; ++t) {
            S16 B;
            B.u4 = Bt[t];
            f32x4 c0 = __builtin_amdgcn_mfma_f32_16x16x32_f16(Ah0.h, B.h, bv0, 0, 0, 0);
            f32x4 c1 = __builtin_amdgcn_mfma_f32_16x16x32_f16(Ah1.h, B.h, bv1, 0, 0, 0);
            Bt[t].x = pk2(__builtin_amdgcn_sinf(c0[0]), __builtin_amdgcn_sinf(c0[1]));
            Bt[t].y = pk2(__builtin_amdgcn_sinf(c0[2]), __builtin_amdgcn_sinf(c0[3]));
            Bt[t].z = pk2(__builtin_amdgcn_sinf(c1[0]), __builtin_amdgcn_sinf(c1[1]));
            Bt[t].w = pk2(__builtin_amdgcn_sinf(c1[2]), __builtin_amdgcn_sinf(c1[3]));
        }
    }

    // ---- L5 (32->16) + final (16->3): registers + shfl butterfly ----
    {
        S16 Ah5;
        Ah5.u4 = Af5;
        const f32x4 bv5 = bias_frag(b5, 0, q);
        float4 wfl[3];
#pragma unroll
        for (int c = 0; c < 3; ++c)
            wfl[c] = *reinterpret_cast<const float4*>(&wf[c * 16 + 4 * q]);

        float red[8][3];
#pragma unroll
        for (int t = 0; t < 8; ++t) {
            S16 B;
            B.u4 = Bt[t];
            f32x4 c5 = __builtin_amdgcn_mfma_f32_16x16x32_f16(Ah5.h, B.h, bv5, 0, 0, 0);
            float h0 = __builtin_amdgcn_sinf(c5[0]);
            float h1 = __builtin_amdgcn_sinf(c5[1]);
            float h2 = __builtin_amdgcn_sinf(c5[2]);
            float h3 = __builtin_amdgcn_sinf(c5[3]);
#pragma unroll
            for (int c = 0; c < 3; ++c)
                red[t][c] = fmaf(wfl[c].x, h0, fmaf(wfl[c].y, h1,
                            fmaf(wfl[c].z, h2, wfl[c].w * h3)));
        }
        // butterfly over the 4 q-lanes sharing a point column
#pragma unroll
        for (int t = 0; t < 8; ++t)
#pragma unroll
            for (int c = 0; c < 3; ++c) {
                float v = red[t][c];
                v += __shfl_xor(v, 16, 64);
                v += __shfl_xor(v, 32, 64);
                red[t][c] = v;
            }
        // lane outputs two points: t=q (pts 0..63) and t=4+q (pts 64..127)
        float o0[3], o1[3];
#pragma unroll
        for (int c = 0; c < 3; ++c) {
            float v01 = (q & 1) ? red[1][c] : red[0][c];
            float v23 = (q & 1) ? red[3][c] : red[2][c];
            o0[c] = fast_sigmoid(((q & 2) ? v23 : v01) + bfin[c]);
            float w01 = (q & 1) ? red[5][c] : red[4][c];
            float w23 = (q & 1) ? red[7][c] : red[6][c];
            o1[c] = fast_sigmoid(((q & 2) ? w23 : w01) + bfin[c]);
        }
        const int p0 = pbase + 16 * q + nl;
        const int p1 = p0 + 64;
        if (p0 < n) {
            out[3 * p0 + 0] = o0[0];
            out[3 * p0 + 1] = o0[1];
            out[3 * p0 + 2] = o0[2];
        }
        if (p1 < n) {
            out[3 * p1 + 0] = o1[0];
            out[3 * p1 + 1] = o1[1];
            out[3 * p1 + 2] = o1[2];
        }
    }
}

extern "C" void kernel_launch(void* const* d_in, const int* in_sizes, int n_in,
                              void* d_out, int out_size, void* d_ws, size_t ws_size,
                              hipStream_t stream) {
    const float* coords = (const float*)d_in[0];
    const float* w0 = (const float*)d_in[1];
    const float* b0 = (const float*)d_in[2];
    const float* w1 = (const float*)d_in[3];
    const float* b1 = (const float*)d_in[4];
    const float* w2 = (const float*)d_in[5];
    const float* b2 = (const float*)d_in[6];
    const float* w3 = (const float*)d_in[7];
    const float* b3 = (const float*)d_in[8];
    const float* w4 = (const float*)d_in[9];
    const float* b4 = (const float*)d_in[10];
    const float* w5 = (const float*)d_in[11];
    const float* b5 = (const float*)d_in[12];
    const float* wf = (const float*)d_in[13];
    const float* bf = (const float*)d_in[14];
    float* out = (float*)d_out;

    const int n = in_sizes[0] / 2;

    siren_mfma<<<(n + 511) / 512, 256, 0, stream>>>(
        coords, w0, b0, w1, b1, w2, b2, w3, b3, w4, b4, w5, b5, wf, bf, out, n);
}